// Round 5
// baseline (778.985 us; speedup 1.0000x reference)
//
#include <hip/hip_runtime.h>

// EmbeddingLSQ: out[t,d] = (idx[t]==0) ? 0 : rint(clamp(W[d,idx[t]]/a,-8,7))*a
// idx[t] = position of the 1.0 in one-hot row x[t,:].
//
// Two-phase to make every HBM line of W fetched exactly once:
//  A) scan_kernel: 1 wave/token, ballot early-exit scan of x row, writes
//     idx[t] -> d_ws.  Expected x traffic: 50% of 524 MB = 262 MB.
//  B) gather_kernel: 1 block per 32-column vocab bucket (1000 blocks). Block
//     collects tokens with idx in its bucket (idx array is 16 KB, L2-hit),
//     then per token gathers w[d, idx] over all 1024 dims (each (d,bucket)
//     line fetched once, reused by co-bucket tokens via L1/L2), quantizes,
//     and writes the 4 KB output row coalesced (float4/lane).

typedef float v4f __attribute__((ext_vector_type(4)));

constexpr int VOCAB  = 32000;
constexpr int DIM    = 1024;
constexpr int TOKENS = 4096;
constexpr int V4     = VOCAB / 4;        // 8000 16B chunks per x row
constexpr int WAVE   = 64;
constexpr int FULL8      = V4 / 512;     // 15 windows of 512 chunks (8 KB)
constexpr int TAIL_BASE  = FULL8 * 512;  // 7680; tail = 320 chunks = 5/lane
constexpr int BUCKET_COLS = 32;          // 128 B of a w row
constexpr int NBUCKETS   = VOCAB / BUCKET_COLS;  // 1000

__device__ __forceinline__ int check4(v4f v, int chunk) {
    if (v.x > 0.5f) return 4 * chunk + 0;
    if (v.y > 0.5f) return 4 * chunk + 1;
    if (v.z > 0.5f) return 4 * chunk + 2;
    if (v.w > 0.5f) return 4 * chunk + 3;
    return -1;
}

// ---- Kernel A: one wave per token, find one-hot index ----
__global__ __launch_bounds__(WAVE) void scan_kernel(
    const float* __restrict__ x, int* __restrict__ idxs)
{
    const int t    = blockIdx.x;
    const int lane = threadIdx.x;
    const v4f* xr = reinterpret_cast<const v4f*>(x + (size_t)t * VOCAB);

    int found = -1;
    for (int k = 0; k < FULL8; ++k) {
        const int i = lane + 512 * k;
        v4f a0 = xr[i];            // 8 x 16B loads in flight (8 KB/wave)
        v4f a1 = xr[i +  64];
        v4f a2 = xr[i + 128];
        v4f a3 = xr[i + 192];
        v4f a4 = xr[i + 256];
        v4f a5 = xr[i + 320];
        v4f a6 = xr[i + 384];
        v4f a7 = xr[i + 448];
        int f;
        if      ((f = check4(a0, i      )) >= 0) found = f;
        else if ((f = check4(a1, i +  64)) >= 0) found = f;
        else if ((f = check4(a2, i + 128)) >= 0) found = f;
        else if ((f = check4(a3, i + 192)) >= 0) found = f;
        else if ((f = check4(a4, i + 256)) >= 0) found = f;
        else if ((f = check4(a5, i + 320)) >= 0) found = f;
        else if ((f = check4(a6, i + 384)) >= 0) found = f;
        else if ((f = check4(a7, i + 448)) >= 0) found = f;
        if (__ballot(found >= 0)) break;     // register-only exit
    }
    if (!__ballot(found >= 0)) {             // tail: 320 chunks, 5 per lane
        #pragma unroll
        for (int j = 0; j < 5; ++j) {
            const int c = TAIL_BASE + lane + 64 * j;
            v4f a = xr[c];
            int f = check4(a, c);
            if (f >= 0) found = f;
        }
    }
    unsigned long long m = __ballot(found >= 0);
    int idx = m ? __shfl(found, (int)__ffsll(m) - 1) : 0;
    if (idx < 0) idx = 0;
    if (lane == 0) idxs[t] = idx;
}

// ---- Kernel B: one block per vocab bucket; fetch each w line once ----
__global__ __launch_bounds__(256) void gather_kernel(
    const float* __restrict__ w,
    const float* __restrict__ alpha,
    const int* __restrict__ idxs,
    float* __restrict__ out)
{
    const int b   = blockIdx.x;
    const int tid = threadIdx.x;

    __shared__ int s_cnt;
    __shared__ int s_list[TOKENS];           // worst case: all tokens one bucket
    if (tid == 0) s_cnt = 0;
    __syncthreads();

    for (int i = tid; i < TOKENS; i += 256) {
        int id = idxs[i];
        if ((id >> 5) == b) {                // idx in [32b, 32b+32)
            int p = atomicAdd(&s_cnt, 1);
            s_list[p] = (i << 15) | id;      // pack token(12b) | idx(15b)
        }
    }
    __syncthreads();

    const int m = s_cnt;
    if (m == 0) return;
    const float a = alpha[0];

    for (int k = 0; k < m; ++k) {
        const int pk  = s_list[k];
        const int t   = pk >> 15;
        const int col = pk & 0x7fff;
        v4f* orow = reinterpret_cast<v4f*>(out + (size_t)t * DIM);
        if (col == 0) {                      // PAD_IDX -> zero row
            v4f z = 0.f;
            orow[tid] = z;
        } else {
            const int d0 = 4 * tid;          // DIM/4 == 256
            float w0 = w[(size_t)(d0 + 0) * VOCAB + col];  // 4 line-gathers
            float w1 = w[(size_t)(d0 + 1) * VOCAB + col];  // (reused by later
            float w2 = w[(size_t)(d0 + 2) * VOCAB + col];  //  k via L1/L2)
            float w3 = w[(size_t)(d0 + 3) * VOCAB + col];
            v4f q;
            q.x = rintf(fminf(fmaxf(w0 / a, -8.f), 7.f)) * a;
            q.y = rintf(fminf(fmaxf(w1 / a, -8.f), 7.f)) * a;
            q.z = rintf(fminf(fmaxf(w2 / a, -8.f), 7.f)) * a;
            q.w = rintf(fminf(fmaxf(w3 / a, -8.f), 7.f)) * a;
            orow[tid] = q;                   // coalesced 4 KB row store
        }
    }
}

extern "C" void kernel_launch(void* const* d_in, const int* in_sizes, int n_in,
                              void* d_out, int out_size, void* d_ws, size_t ws_size,
                              hipStream_t stream) {
    const float* x     = (const float*)d_in[0];   // [TOKENS, VOCAB]
    const float* w     = (const float*)d_in[1];   // [DIM, VOCAB]
    const float* alpha = (const float*)d_in[2];   // [1]
    float* out         = (float*)d_out;           // [TOKENS, DIM]
    int*   idxs        = (int*)d_ws;              // 16 KB scratch

    scan_kernel<<<TOKENS, WAVE, 0, stream>>>(x, idxs);
    gather_kernel<<<NBUCKETS, 256, 0, stream>>>(w, alpha, idxs, out);
}

// Round 6
// 722.456 us; speedup vs baseline: 1.0782x; 1.0782x over previous
//
#include <hip/hip_runtime.h>

// EmbeddingLSQ: out[t,d] = (idx[t]==0) ? 0 : rint(clamp(W[d,idx[t]]/a,-8,7))*a
// idx[t] = position of the 1.0 in one-hot row x[t,:].
//
// Layout-transform strategy:
//  Q) quant_kernel: stream W [DIM][VOCAB] once (131 MB, full-line coalesced),
//     quantize to int8 codes in [-8,7], store TRANSPOSED codesT[VOCAB][DIM]
//     (32 MB) into d_ws via LDS tile (line-aligned 128B coalesced writes).
//  S) scan_gather_kernel: 1 wave/token ballot-early-exit scan of x (R4
//     structure), then token's embedding = 1 KB CONTIGUOUS read of
//     codesT[idx][:] (4 x 256B coalesced dword loads), decode (float)code*a,
//     4 coalesced 16B stores/lane. Gather traffic: 537 MB scattered -> 4 MB.

typedef float v4f __attribute__((ext_vector_type(4)));
typedef int   v4i __attribute__((ext_vector_type(4)));

constexpr int VOCAB  = 32000;
constexpr int DIM    = 1024;
constexpr int TOKENS = 4096;
constexpr int V4     = VOCAB / 4;        // 8000 16B chunks per x row
constexpr int WAVE   = 64;
constexpr int FULL_ITERS = V4 / 256;     // 31 windows of 256 chunks (4 KB)
constexpr int TAIL_BASE  = FULL_ITERS * 256;  // 7936; tail = 64 chunks

// ---- Kernel Q: quantize W -> int8 codesT[VOCAB][DIM] (transposed) ----
// Tile: 128 dims x 32 cols. 32 cols * 4B = 128 B = exactly one cache line,
// so each block consumes whole lines of W (no cross-block line sharing).
__global__ __launch_bounds__(256) void quant_kernel(
    const float* __restrict__ w,
    const float* __restrict__ alpha,
    signed char* __restrict__ codes)
{
    const int c0 = blockIdx.x * 32;      // vocab tile base (128B-aligned cols)
    const int d0 = blockIdx.y * 128;     // dim tile base
    const int tid = threadIdx.x;
    const float a = alpha[0];

    __shared__ alignas(16) signed char s_tile[32][128];  // [col][dim]

    // Load + quantize: 2 threads per dim row, 4x16B each (full 128B line).
    const int r = tid >> 1;              // 0..127 local dim
    const int p = tid & 1;               // half-line select
    const v4f* wr = reinterpret_cast<const v4f*>(
        w + (size_t)(d0 + r) * VOCAB + c0 + 16 * p);
    #pragma unroll
    for (int q = 0; q < 4; ++q) {
        v4f v = wr[q];
        const int cl = 16 * p + 4 * q;   // local col of v.x
        s_tile[cl + 0][r] = (signed char)(int)rintf(fminf(fmaxf(v.x / a, -8.f), 7.f));
        s_tile[cl + 1][r] = (signed char)(int)rintf(fminf(fmaxf(v.y / a, -8.f), 7.f));
        s_tile[cl + 2][r] = (signed char)(int)rintf(fminf(fmaxf(v.z / a, -8.f), 7.f));
        s_tile[cl + 3][r] = (signed char)(int)rintf(fminf(fmaxf(v.w / a, -8.f), 7.f));
    }
    __syncthreads();

    // Write transposed: 8 threads per col, 16B each -> 128B contiguous/col.
    const int c = tid >> 3;              // 0..31 local col
    const int k = tid & 7;               // 16B chunk within the 128-dim row
    const v4i* src = reinterpret_cast<const v4i*>(&s_tile[c][16 * k]);
    v4i* dst = reinterpret_cast<v4i*>(codes + (size_t)(c0 + c) * DIM + d0 + 16 * k);
    *dst = *src;
}

__device__ __forceinline__ int check4(v4f v, int chunk) {
    if (v.x > 0.5f) return 4 * chunk + 0;
    if (v.y > 0.5f) return 4 * chunk + 1;
    if (v.z > 0.5f) return 4 * chunk + 2;
    if (v.w > 0.5f) return 4 * chunk + 3;
    return -1;
}

// ---- Kernel S: wave/token scan + contiguous code gather ----
__global__ __launch_bounds__(WAVE) void scan_gather_kernel(
    const float* __restrict__ x,
    const signed char* __restrict__ codes,
    const float* __restrict__ alpha,
    float* __restrict__ out)
{
    const int t    = blockIdx.x;
    const int lane = threadIdx.x;

    // Phase 1: find one-hot index (R4 structure: 4 KB windows, ballot exit)
    const v4f* xr = reinterpret_cast<const v4f*>(x + (size_t)t * VOCAB);
    int found = -1;
    for (int k = 0; k < FULL_ITERS; ++k) {
        const int i = lane + 256 * k;
        v4f a0 = xr[i];
        v4f a1 = xr[i +  64];
        v4f a2 = xr[i + 128];
        v4f a3 = xr[i + 192];
        int f;
        if      ((f = check4(a0, i      )) >= 0) found = f;
        else if ((f = check4(a1, i +  64)) >= 0) found = f;
        else if ((f = check4(a2, i + 128)) >= 0) found = f;
        else if ((f = check4(a3, i + 192)) >= 0) found = f;
        if (__ballot(found >= 0)) break;
    }
    if (!__ballot(found >= 0)) {
        v4f a = xr[TAIL_BASE + lane];
        found = check4(a, TAIL_BASE + lane);
    }
    unsigned long long m = __ballot(found >= 0);
    const int idx = m ? __shfl(found, (int)__ffsll(m) - 1) : 0;

    // Phase 2: contiguous 1 KB code row -> decode -> coalesced stores
    v4f* orow = reinterpret_cast<v4f*>(out + (size_t)t * DIM);
    if (idx <= 0) {                          // PAD_IDX -> zero row
        v4f z = 0.f;
        #pragma unroll
        for (int j = 0; j < 4; ++j) orow[lane + 64 * j] = z;
    } else {
        const float a = alpha[0];
        const unsigned* crow = reinterpret_cast<const unsigned*>(
            codes + (size_t)idx * DIM);
        unsigned u[4];
        #pragma unroll
        for (int j = 0; j < 4; ++j) u[j] = crow[lane + 64 * j];  // 256B coalesced
        #pragma unroll
        for (int j = 0; j < 4; ++j) {
            v4f q;
            q.x = (float)(signed char)(u[j]      ) * a;
            q.y = (float)(signed char)(u[j] >>  8) * a;
            q.z = (float)(signed char)(u[j] >> 16) * a;
            q.w = (float)(signed char)(u[j] >> 24) * a;
            orow[lane + 64 * j] = q;         // 1 KB coalesced store/instr
        }
    }
}

extern "C" void kernel_launch(void* const* d_in, const int* in_sizes, int n_in,
                              void* d_out, int out_size, void* d_ws, size_t ws_size,
                              hipStream_t stream) {
    const float* x     = (const float*)d_in[0];   // [TOKENS, VOCAB]
    const float* w     = (const float*)d_in[1];   // [DIM, VOCAB]
    const float* alpha = (const float*)d_in[2];   // [1]
    float* out         = (float*)d_out;           // [TOKENS, DIM]
    signed char* codes = (signed char*)d_ws;      // 32 MB codesT[VOCAB][DIM]

    dim3 qgrid(VOCAB / 32, DIM / 128);            // 1000 x 8 tiles
    quant_kernel<<<qgrid, 256, 0, stream>>>(w, alpha, codes);
    scan_gather_kernel<<<TOKENS, WAVE, 0, stream>>>(x, codes, alpha, out);
}